// Round 4
// baseline (409.549 us; speedup 1.0000x reference)
//
#include <hip/hip_runtime.h>
#include <math.h>
#include <limits.h>

// ---- problem constants ----
#define C_IN 256
#define HM_H 136
#define HM_W 240
#define HM_N (HM_H * HM_W)      // 32640
#define MB   64
#define MH   272
#define MW   480
#define MN   (MH * MW)          // 130560
#define NP   134
#define NI   4
#define HID  64

// d_out layout (floats): scores[4] | inds[4] | regs0[4*MN] | masks0[4*MN] | feat[4*480*2]
#define REG_OFF   8
#define MASK_OFF  (8 + NI * MN)
#define FEAT_OFF  (8 + 2 * NI * MN)

// ws layout (floats)
#define WS_HM   0
#define WS_CV   HM_N                      // 512 cand values
#define WS_CI   (HM_N + 512)              // 512 cand indices
#define WS_GP   (2 * HM_N)                // 536 gen params
#define WS_INDS (2 * HM_N + NI * NP)      // 4 ints
#define WS_CNT  (WS_INDS + 4)             // 1 uint ticket counter
#define WS_WT_F 65824                     // bf16 weight table (147456 ushorts)

typedef float  f32x4  __attribute__((ext_vector_type(4)));
typedef short  bf16x8 __attribute__((ext_vector_type(8)));

__device__ __forceinline__ unsigned short f2bf(float f) {
  unsigned int u = __float_as_uint(f);
  u += 0x7FFFu + ((u >> 16) & 1u);
  return (unsigned short)(u >> 16);
}
__device__ __forceinline__ float b2f(unsigned short h) {
  return __uint_as_float(((unsigned int)h) << 16);
}
__device__ __forceinline__ unsigned int pk2(float lo, float hi) {
  return (unsigned int)f2bf(lo) | ((unsigned int)f2bf(hi) << 16);
}

// ------------------------------------------------------------------
// K_pre: fused (a) weight swizzle to MFMA B-frag order, (b) hm head,
// (c) zero the ticket counter.
// ------------------------------------------------------------------
__global__ void k_pre(const float* __restrict__ mb_w, unsigned short* __restrict__ wt,
                      const float* __restrict__ out1, const float* __restrict__ hm_w,
                      const float* __restrict__ hm_b, float* __restrict__ ws_hm,
                      unsigned int* __restrict__ cnt) {
  __shared__ float part[4][64];
  int b = blockIdx.x, t = threadIdx.x;
  if (b == 0 && t == 0) *cnt = 0;
  if (b < 576) {
    int idx = b * 256 + t;                 // 147456 total
    int j    = idx & 7;
    int lane = (idx >> 3) & 63;
    int nt   = (idx >> 9) & 3;
    int gt   = idx >> 11;
    int tp   = gt % 9;
    int g    = gt / 9;
    int n = nt * 16 + (lane & 15);
    int c = g * 32 + (lane >> 4) * 8 + j;
    wt[idx] = f2bf(mb_w[(n * C_IN + c) * 9 + tp]);
  } else {
    int bb = b - 576;                      // 510 blocks
    int cg = t >> 6, pl = t & 63;
    int p = bb * 64 + pl;
    float s = 0.f;
    #pragma unroll 16
    for (int c = 0; c < 64; ++c)
      s += hm_w[cg * 64 + c] * out1[(cg * 64 + c) * HM_N + p];
    part[cg][pl] = s;
    __syncthreads();
    if (t < 64) {
      float tot = part[0][t] + part[1][t] + part[2][t] + part[3][t] + hm_b[0];
      float sig = 1.f / (1.f + expf(-tot));
      sig = fminf(fmaxf(sig, 1e-4f), 1.f - 1e-4f);
      ws_hm[bb * 64 + t] = sig;
    }
  }
}

// ------------------------------------------------------------------
// top-4 helpers
// ------------------------------------------------------------------
__device__ __forceinline__ bool better(float av, int ai, float bv, int bi) {
  return (av > bv) || (av == bv && ai < bi);
}

template<int NTHR>
__device__ void top4_tree(float* sv, int* si, int t) {
  for (int s = NTHR / 2; s >= 1; s >>= 1) {
    if (t < s) {
      float a[4], b[4]; int ai[4], bj[4];
      #pragma unroll
      for (int k = 0; k < 4; ++k) {
        a[k] = sv[t * 4 + k];        ai[k] = si[t * 4 + k];
        b[k] = sv[(t + s) * 4 + k];  bj[k] = si[(t + s) * 4 + k];
      }
      float ov[4]; int oi[4];
      int i = 0, j = 0;
      #pragma unroll
      for (int k = 0; k < 4; ++k) {
        if (better(a[i], ai[i], b[j], bj[j])) { ov[k] = a[i]; oi[k] = ai[i]; ++i; }
        else                                   { ov[k] = b[j]; oi[k] = bj[j]; ++j; }
      }
      #pragma unroll
      for (int k = 0; k < 4; ++k) { sv[t * 4 + k] = ov[k]; si[t * 4 + k] = oi[k]; }
    }
    __syncthreads();
  }
}

// ------------------------------------------------------------------
// K_nms_merge: NMS + per-block top4; last block (atomic ticket) merges all
// candidates, writes scores/inds, and computes gen_params for the 4 winners.
// ------------------------------------------------------------------
__global__ void k_nms_merge(const float* __restrict__ ws_hm, float* __restrict__ candv,
                            int* __restrict__ candi, unsigned int* __restrict__ cnt,
                            const float* __restrict__ out1, const float* __restrict__ params_w,
                            const float* __restrict__ params_b, int* __restrict__ ws_inds,
                            float* __restrict__ ws_gp, float* __restrict__ d_out) {
  __shared__ float sv[256 * 4];
  __shared__ int   si[256 * 4];
  __shared__ int   lastFlag;
  __shared__ float col[4][C_IN];
  int b = blockIdx.x, t = threadIdx.x;

  float v = -1.f; int idx = INT_MAX;
  if (t < 255) {
    int p = b * 255 + t;
    int y = p / HM_W, x = p - y * HM_W;
    float c = ws_hm[p], m = c;
    #pragma unroll
    for (int dy = -1; dy <= 1; ++dy)
      #pragma unroll
      for (int dx = -1; dx <= 1; ++dx) {
        int yy = y + dy, xx = x + dx;
        if (yy >= 0 && yy < HM_H && xx >= 0 && xx < HM_W)
          m = fmaxf(m, ws_hm[yy * HM_W + xx]);
      }
    v = (c == m) ? c : 0.f;
    idx = p;
  }
  sv[t * 4] = v; si[t * 4] = idx;
  #pragma unroll
  for (int k = 1; k < 4; ++k) { sv[t * 4 + k] = -1.f; si[t * 4 + k] = INT_MAX; }
  __syncthreads();
  top4_tree<256>(sv, si, t);
  if (t == 0) {
    #pragma unroll
    for (int k = 0; k < 4; ++k) { candv[b * 4 + k] = sv[k]; candi[b * 4 + k] = si[k]; }
    __threadfence();
    unsigned int tk = atomicAdd(cnt, 1u);
    lastFlag = (tk == 127u);
  }
  __syncthreads();
  if (!lastFlag) return;
  __threadfence();

  // final merge of 128 x 4 candidates
  if (t < 128) {
    #pragma unroll
    for (int k = 0; k < 4; ++k) { sv[t * 4 + k] = candv[t * 4 + k]; si[t * 4 + k] = candi[t * 4 + k]; }
  }
  __syncthreads();
  top4_tree<128>(sv, si, t);
  if (t == 0) {
    #pragma unroll
    for (int k = 0; k < 4; ++k) {
      d_out[k]     = sv[k];
      d_out[4 + k] = (float)si[k];
      ws_inds[k]   = si[k];
    }
  }
  __syncthreads();

  // gen_params for the 4 winners
  #pragma unroll
  for (int i = 0; i < NI; ++i) col[i][t] = out1[t * HM_N + si[i]];
  __syncthreads();
  for (int o = t; o < NI * NP; o += 256) {
    int i = o / NP, j = o - i * NP;
    float s = params_b[j];
    #pragma unroll 8
    for (int c = 0; c < C_IN; ++c) s += params_w[j * C_IN + c] * col[i][c];
    ws_gp[i * NP + j] = s;
  }
}

// ------------------------------------------------------------------
// K_conv: MFMA implicit-GEMM conv, single LDS buffer + register pipeline.
// Tile 8x32 px; stage 10 rows x 36 x x 32 c bf16, pixel stride 40 ushorts.
// Units: (c-pair, row, x-pair) = 16*10*18 = 2880; 12 units/thread.
// ------------------------------------------------------------------
#define RP 36
#define CSU 20     // pixel stride in u32 (40 ushorts = 80 B)
#define NUNIT 2880
#define UPT 12
#define ES 66

__global__ __launch_bounds__(256, 3) void k_conv_mfma(
    const float* __restrict__ out0, const unsigned short* __restrict__ wt,
    const float* __restrict__ mb_b, const float* __restrict__ ws_gp,
    float* __restrict__ d_out) {
  __shared__ char smraw[33792] __attribute__((aligned(16)));   // stage 28800 B / epi 33792 B
  unsigned int*   lds32 = (unsigned int*)smraw;
  unsigned short* lds16 = (unsigned short*)smraw;

  int tid  = threadIdx.x;
  int lane = tid & 63;
  int w    = tid >> 6;
  int n15  = lane & 15;
  int kq   = lane >> 4;
  int gx0 = blockIdx.x * 32, gy0 = blockIdx.y * 8;

  // staging descriptors
  int goff[UPT], lofs[UPT];
  unsigned int vmask = 0, smask0 = 0, smask1 = 0;
  #pragma unroll
  for (int i = 0; i < UPT; ++i) {
    int u = tid + 256 * i;
    bool vu = (u < NUNIT);
    int c2  = u / 180;
    int rem = u - c2 * 180;
    int row = rem / 18;
    int q   = rem - row * 18;
    int iy  = gy0 + row - 1;
    int ixe = gx0 + 2 * q - 2;
    bool vld = vu && iy >= 0 && iy < MH && ixe >= 0 && (ixe + 1) < MW;
    goff[i] = vld ? (2 * c2 * MN + iy * MW + ixe) : 0;
    if (vld) vmask |= (1u << i);
    int x0 = 2 * q - 1;
    lofs[i] = (row * RP + x0) * CSU + c2;
    if (vu && x0 >= 0) smask0 |= (1u << i);
    if (vu)            smask1 |= (1u << i);
  }

  // A-frag geometry
  int rrow[4], xbas[4];
  #pragma unroll
  for (int i = 0; i < 4; ++i) {
    int mt = w * 4 + i;
    rrow[i] = mt >> 1;
    xbas[i] = (mt & 1) * 16 + n15;
  }

  // prologue: load + pack g=0
  unsigned int pkA[UPT], pkB[UPT];
  {
    float2 rA[UPT], rB[UPT];
    #pragma unroll
    for (int i = 0; i < UPT; ++i) {
      rA[i] = *(const float2*)(out0 + goff[i]);
      rB[i] = *(const float2*)(out0 + goff[i] + MN);
    }
    #pragma unroll
    for (int i = 0; i < UPT; ++i) {
      bool vl = (vmask >> i) & 1;
      pkA[i] = vl ? pk2(rA[i].x, rB[i].x) : 0u;
      pkB[i] = vl ? pk2(rA[i].y, rB[i].y) : 0u;
    }
  }

  f32x4 acc[4][4];
  #pragma unroll
  for (int i = 0; i < 4; ++i)
    #pragma unroll
    for (int nt = 0; nt < 4; ++nt)
      acc[i][nt] = (f32x4){0.f, 0.f, 0.f, 0.f};

  #pragma unroll 1
  for (int g = 0; g < 8; ++g) {
    __syncthreads();                       // LDS consumed by previous MFMA phase
    #pragma unroll
    for (int i = 0; i < UPT; ++i) {
      if ((smask0 >> i) & 1) lds32[lofs[i]]       = pkA[i];
      if ((smask1 >> i) & 1) lds32[lofs[i] + CSU] = pkB[i];
    }
    __syncthreads();

    const float* src = out0 + (g + 1) * (32 * MN);
    float2 rA[6], rB[6];
    if (g < 7) {
      #pragma unroll
      for (int i = 0; i < 6; ++i) {
        rA[i] = *(const float2*)(src + goff[i]);
        rB[i] = *(const float2*)(src + goff[i] + MN);
      }
    }
    #pragma unroll
    for (int t = 0; t < 4; ++t) {
      int ty = t / 3, tx = t - ty * 3;
      const unsigned short* wb = wt + (g * 9 + t) * 2048 + lane * 8;
      bf16x8 bfrag[4], afrag[4];
      #pragma unroll
      for (int nt = 0; nt < 4; ++nt) bfrag[nt] = *(const bf16x8*)(wb + nt * 512);
      #pragma unroll
      for (int i = 0; i < 4; ++i)
        afrag[i] = *(const bf16x8*)&lds16[((rrow[i] + ty) * RP + xbas[i] + tx) * 40 + kq * 8];
      #pragma unroll
      for (int i = 0; i < 4; ++i)
        #pragma unroll
        for (int nt = 0; nt < 4; ++nt)
          acc[i][nt] = __builtin_amdgcn_mfma_f32_16x16x32_bf16(afrag[i], bfrag[nt], acc[i][nt], 0, 0, 0);
    }
    if (g < 7) {
      #pragma unroll
      for (int i = 0; i < 6; ++i) {
        bool vl = (vmask >> i) & 1;
        pkA[i] = vl ? pk2(rA[i].x, rB[i].x) : 0u;
        pkB[i] = vl ? pk2(rA[i].y, rB[i].y) : 0u;
      }
      #pragma unroll
      for (int i = 6; i < UPT; ++i) {
        rA[i - 6] = *(const float2*)(src + goff[i]);
        rB[i - 6] = *(const float2*)(src + goff[i] + MN);
      }
    }
    #pragma unroll
    for (int t = 4; t < 9; ++t) {
      int ty = t / 3, tx = t - ty * 3;
      const unsigned short* wb = wt + (g * 9 + t) * 2048 + lane * 8;
      bf16x8 bfrag[4], afrag[4];
      #pragma unroll
      for (int nt = 0; nt < 4; ++nt) bfrag[nt] = *(const bf16x8*)(wb + nt * 512);
      #pragma unroll
      for (int i = 0; i < 4; ++i)
        afrag[i] = *(const bf16x8*)&lds16[((rrow[i] + ty) * RP + xbas[i] + tx) * 40 + kq * 8];
      #pragma unroll
      for (int i = 0; i < 4; ++i)
        #pragma unroll
        for (int nt = 0; nt < 4; ++nt)
          acc[i][nt] = __builtin_amdgcn_mfma_f32_16x16x32_bf16(afrag[i], bfrag[nt], acc[i][nt], 0, 0, 0);
    }
    if (g < 7) {
      #pragma unroll
      for (int i = 6; i < UPT; ++i) {
        bool vl = (vmask >> i) & 1;
        pkA[i] = vl ? pk2(rA[i - 6].x, rB[i - 6].x) : 0u;
        pkB[i] = vl ? pk2(rA[i - 6].y, rB[i - 6].y) : 0u;
      }
    }
  }

  // epilogue: bias+relu, acc -> LDS [pixel][channel] bf16
  float bias[4];
  #pragma unroll
  for (int nt = 0; nt < 4; ++nt) bias[nt] = mb_b[nt * 16 + n15];
  __syncthreads();
  #pragma unroll
  for (int i = 0; i < 4; ++i) {
    int mt = w * 4 + i;
    int pbase = (mt >> 1) * 32 + (mt & 1) * 16;
    #pragma unroll
    for (int nt = 0; nt < 4; ++nt)
      #pragma unroll
      for (int reg = 0; reg < 4; ++reg) {
        float vv = fmaxf(acc[i][nt][reg] + bias[nt], 0.f);
        lds16[(pbase + kq * 4 + reg) * ES + nt * 16 + n15] = f2bf(vv);
      }
  }
  __syncthreads();

  // dynamic heads: thread tid owns pixel tid
  int r = tid >> 5, xcol = tid & 31;
  int gy = gy0 + r, gx = gx0 + xcol;
  float xc = -1.f + (2.f / 479.f) * (float)gx;
  float yc = -1.f + (2.f / 271.f) * (float)gy;
  float mres[4] = {0.f, 0.f, 0.f, 0.f};
  float rres[4] = {0.f, 0.f, 0.f, 0.f};
  #pragma unroll 8
  for (int o = 0; o < MB; ++o) {
    float v = b2f(lds16[tid * ES + o]);
    #pragma unroll
    for (int i = 0; i < 4; ++i) {
      mres[i] += ws_gp[i * NP + o] * v;
      rres[i] += ws_gp[i * NP + 67 + o] * v;
    }
  }
  int pix = gy * MW + gx;
  #pragma unroll
  for (int i = 0; i < 4; ++i) {
    const float* g = ws_gp + i * NP;
    d_out[MASK_OFF + i * MN + pix] = mres[i] + g[66]  + g[64]  * xc + g[65]  * yc;
    d_out[REG_OFF  + i * MN + pix] = rres[i] + g[133] + g[131] * xc + g[132] * yc;
  }
}

// ------------------------------------------------------------------
// K_mlp: feat_range MLP
// ------------------------------------------------------------------
__global__ void k_mlp(const float* __restrict__ masks0, const float* __restrict__ w1,
                      const float* __restrict__ b1, const float* __restrict__ w2,
                      const float* __restrict__ b2, float* __restrict__ d_out) {
  int blk = blockIdx.x;          // i*480 + w
  int i = blk / MW;
  int w = blk - i * MW;
  int k = threadIdx.x;           // 0..63
  const float* mcol = masks0 + i * MN + w;
  float s = b1[k];
  for (int h = 0; h < MH; ++h) s += mcol[h * MW] * w1[h * HID + k];
  s = fmaxf(s, 0.f);
  float o0 = s * w2[k * 2 + 0];
  float o1 = s * w2[k * 2 + 1];
  #pragma unroll
  for (int off = 32; off >= 1; off >>= 1) {
    o0 += __shfl_down(o0, off);
    o1 += __shfl_down(o1, off);
  }
  if (k == 0) {
    d_out[FEAT_OFF + blk * 2 + 0] = o0 + b2[0];
    d_out[FEAT_OFF + blk * 2 + 1] = o1 + b2[1];
  }
}

// ------------------------------------------------------------------
extern "C" void kernel_launch(void* const* d_in, const int* in_sizes, int n_in,
                              void* d_out, int out_size, void* d_ws, size_t ws_size,
                              hipStream_t stream) {
  const float* out0     = (const float*)d_in[0];
  const float* out1     = (const float*)d_in[1];
  const float* hm_w     = (const float*)d_in[2];
  const float* hm_b     = (const float*)d_in[3];
  const float* params_w = (const float*)d_in[4];
  const float* params_b = (const float*)d_in[5];
  const float* mb_w     = (const float*)d_in[6];
  const float* mb_b     = (const float*)d_in[7];
  const float* mlp_w1   = (const float*)d_in[8];
  const float* mlp_b1   = (const float*)d_in[9];
  const float* mlp_w2   = (const float*)d_in[10];
  const float* mlp_b2   = (const float*)d_in[11];

  float* ws      = (float*)d_ws;
  float* ws_hm   = ws + WS_HM;
  float* candv   = ws + WS_CV;
  int*   candi   = (int*)(ws + WS_CI);
  float* ws_gp   = ws + WS_GP;
  int*   ws_inds = (int*)(ws + WS_INDS);
  unsigned int* cnt = (unsigned int*)(ws + WS_CNT);
  unsigned short* ws_wt = (unsigned short*)(ws + WS_WT_F);
  float* out     = (float*)d_out;

  k_pre<<<1086, 256, 0, stream>>>(mb_w, ws_wt, out1, hm_w, hm_b, ws_hm, cnt);
  k_nms_merge<<<128, 256, 0, stream>>>(ws_hm, candv, candi, cnt, out1,
                                       params_w, params_b, ws_inds, ws_gp, out);
  dim3 gconv(MW / 32, MH / 8);   // 15 x 34
  k_conv_mfma<<<gconv, 256, 0, stream>>>(out0, ws_wt, mb_b, ws_gp, out);
  k_mlp<<<NI * MW, 64, 0, stream>>>(out + MASK_OFF, mlp_w1, mlp_b1, mlp_w2, mlp_b2, out);
}